// Round 16
// baseline (114.351 us; speedup 1.0000x reference)
//
#include <hip/hip_runtime.h>
#include <math.h>

// CrowdDet RetinaNet loss constants
#define POS_T 0.5f
#define NEG_T 0.4f
#define F_ALPHA 0.25f
#define SL1_BETA 0.1f
#define SENT 3.0e8f

// Pruning geometry (validated R10-R15): 8x8 cells of 128px, 6 area classes.
#define NCELL 8
#define NCLASS 6
#define NB (NCELL * NCELL * NCLASS)   // 384 buckets
#define KEEP_T 0.37f
#define APT 8                          // anchors per thread in k1/k3

// Anchor legacy-area class thresholds: 289 * 2.5^k (exact in f32).
__device__ __constant__ float AT[7] = {
    289.f, 722.5f, 1806.25f, 4515.625f, 11289.0625f, 28222.65625f, 70556.640625f};

__device__ __forceinline__ float smooth_l1(float d) {
    d = fabsf(d);
    return d < SL1_BETA ? 0.5f * d * d / SL1_BETA : d - SL1_BETA;
}

// Broadcast lane g's value to all lanes (v_readlane, uniform g).
__device__ __forceinline__ float rlf(float x, int g) {
    return __int_as_float(__builtin_amdgcn_readlane(__float_as_int(x), g));
}

__device__ __forceinline__ int bucket_of(const float4 av) {
    const float aw = av.z - av.x + 1.f, ah = av.w - av.y + 1.f;
    const float Aa = aw * ah;
    const float cx = 0.5f * (av.x + av.z);
    const float cy = 0.5f * (av.y + av.w);
    const int cxi = min(NCELL - 1, max(0, (int)(cx * (1.0f / 128.f))));
    const int cyi = min(NCELL - 1, max(0, (int)(cy * (1.0f / 128.f))));
    const int k = (Aa > AT[1]) + (Aa > AT[2]) + (Aa > AT[3])
                + (Aa > AT[4]) + (Aa > AT[5]);
    return (k << 6) | (cyi << 3) | cxi;
}

// ---- K1: anchor buckets + per-block LDS hist; prefill sortedA/wavebkt/ws ---
__global__ __launch_bounds__(256) void k1_assign(
    const float* __restrict__ anchors,
    int* __restrict__ bucketid, int* __restrict__ blockhist, // [nablk][NB]
    int* __restrict__ sortedA, int* __restrict__ wavebkt,
    double* __restrict__ ws,
    int A, int PADTOT, int NWPAD, int nablk)
{
#pragma clang fp contract(off)
    __shared__ int lh[NB];
    const int t = threadIdx.x;
    for (int i = t; i < NB; i += 256) lh[i] = 0;
    __syncthreads();

    const int gid = blockIdx.x * 256 + t;
    if (gid < 50) ws[gid] = 0.0;                 // accumulators + done ctr
    const int stride = nablk * 256;
    for (int j = gid; j < PADTOT; j += stride) sortedA[j] = -1;
    for (int j = gid; j < NWPAD; j += stride) wavebkt[j] = -1;

    const int abase = gid * APT;
    #pragma unroll
    for (int u = 0; u < APT; ++u) {
        const int ai = abase + u;
        if (ai < A) {
            const float4 av = *reinterpret_cast<const float4*>(anchors + 4 * (size_t)ai);
            const int bk = bucket_of(av);
            bucketid[ai] = bk;
            atomicAdd(&lh[bk], 1);               // LDS atomic, cheap
        }
    }
    __syncthreads();
    for (int j = t; j < NB; j += 256)
        blockhist[(size_t)blockIdx.x * NB + j] = lh[j];
}

// ---- K2: per-bucket scan of block hists + SoA candidate lists --------------
// SoA chunk = {G0[8],G1[8],G2P[8],G3P[8],AREA[8]}; lane j of k4 reads
// chunk j>>3, slot j&7 (8-lane groups: 32B-contiguous per component).
__global__ __launch_bounds__(256) void k2_scan_lists(
    int* __restrict__ bh, int* __restrict__ totals,
    const float* __restrict__ gt, const float* __restrict__ im_info,
    int* __restrict__ cnt_arr, float* __restrict__ soa,
    float4* __restrict__ eLo, float* __restrict__ eCls,
    int nablk, int G, int NCH, int B)
{
#pragma clang fp contract(off)
    const int bk = blockIdx.x, t = threadIdx.x;

    // Phase 1: exclusive scan of bh[blk][bk] over blk (nablk <= 256).
    __shared__ int s[256];
    const int v = (t < nablk) ? bh[(size_t)t * NB + bk] : 0;
    s[t] = v;
    __syncthreads();
    for (int d = 1; d < 256; d <<= 1) {
        const int u = (t >= d) ? s[t - d] : 0;
        __syncthreads();
        s[t] += u;
        __syncthreads();
    }
    if (t < nablk) bh[(size_t)t * NB + bk] = s[t] - v;   // exclusive prefix
    if (t == 255) totals[bk] = s[255];

    // Phase 2: candidate lists, one batch per wave (validated keep-test;
    // compaction preserves ascending gt order -> first-max tie-break intact).
    const int wid = t >> 6, lane = t & 63;
    const int cxi = bk & 7, cyi = (bk >> 3) & 7, k = bk >> 6;
    const float cx0 = cxi * 128.f, cx1 = cx0 + 128.f;
    const float cy0 = cyi * 128.f, cy1 = cy0 + 128.f;
    const float Alo = AT[k], Ahi = AT[k + 1];

    for (int b = wid; b < B; b += 4) {
        const int nv = __builtin_amdgcn_readfirstlane((int)im_info[b * 6 + 5]);
        const int li = b * NB + bk;
        float* __restrict__ sb = soa + (size_t)li * NCH * 40;
        const size_t eb = (size_t)li * G;

        int cnt = 0;
        for (int base = 0; base < nv; base += 64) {
            const int j = base + lane;
            bool keep = false;
            float g0 = 0.f, g1 = 0.f, g2 = 0.f, g3 = 0.f, cls = 0.f;
            float area = 0.f, g2p = 0.f, g3p = 0.f;
            if (j < nv) {
                const float* sp = gt + ((size_t)b * G + j) * 5;
                g0 = sp[0]; g1 = sp[1]; g2 = sp[2]; g3 = sp[3]; cls = sp[4];
                area = (g2 - g0 + 1.f) * (g3 - g1 + 1.f);   // exact ref order
                g2p = g2 + 1.f; g3p = g3 + 1.f;             // pre-added +1
                const float wg = g2p - g0;
                const float hg = g3p - g1;
                const float ox = fminf(cx1 + 129.f, g2p) - fmaxf(cx0 - 128.f, g0);
                const float oy = fminf(cy1 + 129.f, g3p) - fmaxf(cy0 - 128.f, g1);
                keep = (ox >= KEEP_T * wg) && (oy >= KEEP_T * hg)
                    && (area >= KEEP_T * Alo) && (KEEP_T * area <= Ahi);
            }
            const unsigned long long m = __ballot(keep);
            if (keep) {
                const int pos = cnt + __popcll(m & ((1ull << lane) - 1ull));
                float* c = sb + (size_t)(pos >> 3) * 40 + (pos & 7);
                c[0] = g0; c[8] = g1; c[16] = g2p; c[24] = g3p; c[32] = area;
                eLo[eb + pos] = make_float4(g0, g1, g2, g3);
                eCls[eb + pos] = cls;
            }
            cnt += __popcll(m);
        }
        if (lane == 0) cnt_arr[li] = cnt;
    }
}

// ---- K3: padded bases + wave->bucket table + place anchors -----------------
__global__ __launch_bounds__(256) void k3_place(
    const int* __restrict__ bucketid, const int* __restrict__ bh,
    const int* __restrict__ totals,
    int* __restrict__ sortedA, int* __restrict__ wavebkt, int A)
{
    __shared__ int lh[NB];
    __shared__ int sbase[NB];
    const int t = threadIdx.x, blk = blockIdx.x;
    for (int i = t; i < NB; i += 256) lh[i] = 0;
    if (t < 64) {
        int carry = 0;
        #pragma unroll
        for (int r = 0; r < NB / 64; ++r) {
            int v = ((totals[r * 64 + t] + 63) >> 6) << 6;   // padded count
            const int orig = v;
            for (int d = 1; d < 64; d <<= 1) {
                const int u = __shfl_up(v, d);
                if (t >= d) v += u;
            }
            sbase[r * 64 + t] = carry + v - orig;   // exclusive padded base
            carry += __shfl(v, 63);
        }
    }
    __syncthreads();

    if (blk == 0) {        // wave->bucket table
        for (int bk = t; bk < NB; bk += 256) {
            const int nw = (totals[bk] + 63) >> 6;
            const int wb = sbase[bk] >> 6;
            for (int w = 0; w < nw; ++w) wavebkt[wb + w] = bk;
        }
    }

    const int abase = (blk * 256 + t) * APT;
    #pragma unroll
    for (int u = 0; u < APT; ++u) {
        const int ai = abase + u;
        if (ai < A) {
            const int bk = bucketid[ai];
            const int lrk = atomicAdd(&lh[bk], 1);
            sortedA[sbase[bk] + bh[(size_t)blk * NB + bk] + lrk] = ai;
        }
    }
}

// ---- K4: main loss. Wave = (anchor-wave, batch). Candidate list enters the
//          wave ONCE via per-lane coalesced loads, then v_readlane broadcast
//          (R9-validated pattern) -> zero memory ops in the scan loop. -------
__global__ __launch_bounds__(256) void k4_loss(
    const float* __restrict__ pred_cls, const float* __restrict__ pred_reg,
    const float* __restrict__ anchors,
    const int* __restrict__ sortedA, const int* __restrict__ wavebkt,
    const int* __restrict__ cnt_arr, const float* __restrict__ soa,
    const float4* __restrict__ eLo, const float* __restrict__ eCls,
    int A, int G, int NCH, int B, int NWMAX,
    double* __restrict__ ws, float* __restrict__ out)
{
#pragma clang fp contract(off)
    const int t = threadIdx.x;
    const int lane = t & 63;
    const int wv = __builtin_amdgcn_readfirstlane(blockIdx.x * 4 + (t >> 6));
    const int wgid = wv / B;
    const int b = wv - wgid * B;
    const int bk = (wgid < NWMAX)
        ? __builtin_amdgcn_readfirstlane(wavebkt[wgid]) : -1;

    float lc = 0.f, lr = 0.f;
    int fg = 0;

    if (bk >= 0) {
        const int ai = sortedA[wgid * 64 + lane];    // consecutive -> coalesced
        const bool live = ai >= 0;
        const int a = max(ai, 0);

        const float4 anc = *reinterpret_cast<const float4*>(anchors + 4 * (size_t)a);
        const float a0 = anc.x, a1 = anc.y;
        const float aw = anc.z - anc.x + 1.f;
        const float ah = anc.w - anc.y + 1.f;
        const float area_a = aw * ah;
        const float a2p = anc.z + 1.f;    // +1 pre-added (commutes with min)
        const float a3p = anc.w + 1.f;

        const int li = b * NB + bk;
        const int cnt = __builtin_amdgcn_readfirstlane(cnt_arr[li]);
        const float* lbase = soa + (size_t)li * NCH * 40;

        // Division-free IoU argmax (validated): strict > == first-max;
        // only g < cnt is ever broadcast, so tail lanes need no sentinel.
        float bi = -1.f, bS = 1.f;
        int argp = 0;
        for (int base = 0; base < cnt; base += 64) {
            const int j = base + lane;
            float q0 = 0.f, q1 = 0.f, q2 = 0.f, q3 = 0.f, q4 = 0.f;
            if (j < cnt) {
                const float* cp = lbase + (size_t)(j >> 3) * 40 + (j & 7);
                q0 = cp[0]; q1 = cp[8]; q2 = cp[16]; q3 = cp[24]; q4 = cp[32];
            }
            const int m = min(64, cnt - base);
            for (int g = 0; g < m; ++g) {          // uniform trip count
                const float g0  = rlf(q0, g);      // v_readlane broadcasts
                const float g1  = rlf(q1, g);
                const float g2p = rlf(q2, g);
                const float g3p = rlf(q3, g);
                const float sg  = rlf(q4, g);
                const float iw = fminf(a2p, g2p) - fmaxf(a0, g0);
                const float ih = fminf(a3p, g3p) - fmaxf(a1, g1);
                const float inter = fmaxf(iw, 0.f) * fmaxf(ih, 0.f);
                const float S = area_a + sg;
                const bool upd = inter * bS > bi * S;
                bi   = upd ? inter      : bi;
                bS   = upd ? S          : bS;
                argp = upd ? (base + g) : argp;
            }
        }

        if (live) {
            // ONE division, exact ref expr: inter/((area_a+area_g)-inter).
            // cnt==0 -> max_ov=-0.5 -> bg (validated: pruned ious < 0.37).
            const float max_ov = bi / (bS - bi);

            float label = 0.f;
            bool valid = true;
            if (max_ov >= POS_T) {
                label = eCls[(size_t)li * G + argp];
            } else if (max_ov >= NEG_T) {
                valid = false;                 // ignore band
            }
            const int f = (label > 0.f) ? 1 : 0;
            fg = f;

            if (valid) {
                const float x = pred_cls[(size_t)b * A + a];
                const float p = 1.f / (1.f + expf(-x));
                const float l1p = log1pf(expf(-fabsf(x)));
                const float log_p  = fminf(x, 0.f) - l1p;    // log_sigmoid(x)
                const float log_np = fminf(-x, 0.f) - l1p;   // log_sigmoid(-x)
                const float pos = (label == 1.f) ? 1.f : 0.f;
                const float omp = 1.f - p;
                lc = -(F_ALPHA * pos * (omp * omp) * log_p
                       + (1.f - F_ALPHA) * (1.f - pos) * (p * p) * log_np);
            }

            if (f) {
                const float4 gb = eLo[(size_t)li * G + argp];  // originals
                const float gw = gb.z - gb.x + 1.f;
                const float gh = gb.w - gb.y + 1.f;
                const float gx = gb.x + 0.5f * gw;
                const float gy = gb.y + 0.5f * gh;
                const float axc = a0 + 0.5f * aw;
                const float ayc = a1 + 0.5f * ah;
                const float t0 = (gx - axc) / aw;
                const float t1 = (gy - ayc) / ah;
                const float t2 = logf(gw / aw);
                const float t3 = logf(gh / ah);
                const float4 rr = *reinterpret_cast<const float4*>(
                    pred_reg + 4 * ((size_t)b * A + a));
                lr = smooth_l1(rr.x - t0) + smooth_l1(rr.y - t1)
                   + smooth_l1(rr.z - t2) + smooth_l1(rr.w - t3);
            }
        }
    }

    // wave64 reduction + block atomics + fused last-block finalize (validated).
    for (int off = 32; off > 0; off >>= 1) {
        lc += __shfl_down(lc, off);
        lr += __shfl_down(lr, off);
        fg += __shfl_down(fg, off);
    }
    __shared__ float s_lc[4], s_lr[4];
    __shared__ int s_np[4];
    const int wid = t >> 6;
    if (lane == 0) { s_lc[wid] = lc; s_lr[wid] = lr; s_np[wid] = fg; }
    __syncthreads();
    if (t == 0) {
        const float tlc = s_lc[0] + s_lc[1] + s_lc[2] + s_lc[3];
        const float tlr = s_lr[0] + s_lr[1] + s_lr[2] + s_lr[3];
        const int   tnp = s_np[0] + s_np[1] + s_np[2] + s_np[3];
        __hip_atomic_fetch_add(&ws[0],  (double)tlc, __ATOMIC_RELAXED, __HIP_MEMORY_SCOPE_AGENT);
        __hip_atomic_fetch_add(&ws[16], (double)tlr, __ATOMIC_RELAXED, __HIP_MEMORY_SCOPE_AGENT);
        __hip_atomic_fetch_add(&ws[32], (double)tnp, __ATOMIC_RELAXED, __HIP_MEMORY_SCOPE_AGENT);
        __threadfence();
        int* done = (int*)(ws + 48);
        const int prev = __hip_atomic_fetch_add(done, 1, __ATOMIC_ACQ_REL,
                                                __HIP_MEMORY_SCOPE_AGENT);
        if (prev == (int)gridDim.x - 1) {
            __threadfence();
            const double cls_s = __hip_atomic_load(&ws[0],  __ATOMIC_ACQUIRE, __HIP_MEMORY_SCOPE_AGENT);
            const double reg_s = __hip_atomic_load(&ws[16], __ATOMIC_ACQUIRE, __HIP_MEMORY_SCOPE_AGENT);
            const double np_s  = __hip_atomic_load(&ws[32], __ATOMIC_ACQUIRE, __HIP_MEMORY_SCOPE_AGENT);
            const double npos = np_s < 1.0 ? 1.0 : np_s;
            const double norm = 0.9 * 100.0 + 0.1 * npos;
            out[0] = (float)(cls_s / norm);
            out[1] = (float)(reg_s / norm);
        }
    }
}

extern "C" void kernel_launch(void* const* d_in, const int* in_sizes, int n_in,
                              void* d_out, int out_size, void* d_ws, size_t ws_size,
                              hipStream_t stream) {
    const float* pred_cls = (const float*)d_in[0];
    const float* pred_reg = (const float*)d_in[1];
    const float* anchors  = (const float*)d_in[2];
    const float* gt_boxes = (const float*)d_in[3];
    const float* im_info  = (const float*)d_in[4];

    const int A = in_sizes[2] / 4;
    const int B = in_sizes[4] / 6;
    const int G = in_sizes[3] / (B * 5);
    const int NCH = (G + 7) / 8;                 // chunks per list (ceil)
    const int nablk = ((A + APT - 1) / APT + 255) / 256;   // <= 256 required
    const int PADTOT = A + NB * 64;              // padded sorted-slot bound
    const int NWMAX = (A + 63) / 64 + NB;        // anchor-wave bound
    const int NWPAD = NWMAX + 8;
    const int K4B = (NWMAX * B + 3) / 4;         // 4 waves per block

    // ---- ws layout ----
    char* base = (char*)d_ws;
    double* ws = (double*)base;                  // [0,512): accum + done ctr
    size_t off = 512;
    float* soa = (float*)(base + off);       off += (size_t)B * NB * NCH * 40 * 4;
    off = (off + 255) & ~(size_t)255;
    float4* eLo = (float4*)(base + off);     off += (size_t)B * NB * G * 16;
    float* eCls = (float*)(base + off);      off += (size_t)B * NB * G * 4;
    off = (off + 255) & ~(size_t)255;
    int* cnt_arr = (int*)(base + off);       off += (size_t)B * NB * 4;
    int* bucketid = (int*)(base + off);      off += (size_t)A * 4;
    int* sortedA = (int*)(base + off);       off += (size_t)PADTOT * 4;
    int* wavebkt = (int*)(base + off);       off += (size_t)NWPAD * 4;
    off = (off + 255) & ~(size_t)255;
    int* blockhist = (int*)(base + off);     off += (size_t)nablk * NB * 4;
    int* totals = (int*)(base + off);        off += (size_t)NB * 4;

    k1_assign<<<nablk, 256, 0, stream>>>(anchors, bucketid, blockhist,
                                         sortedA, wavebkt, ws,
                                         A, PADTOT, NWPAD, nablk);
    k2_scan_lists<<<NB, 256, 0, stream>>>(blockhist, totals, gt_boxes, im_info,
                                          cnt_arr, soa, eLo, eCls,
                                          nablk, G, NCH, B);
    k3_place<<<nablk, 256, 0, stream>>>(bucketid, blockhist, totals,
                                        sortedA, wavebkt, A);
    k4_loss<<<K4B, 256, 0, stream>>>(pred_cls, pred_reg, anchors,
                                     sortedA, wavebkt, cnt_arr, soa, eLo, eCls,
                                     A, G, NCH, B, NWMAX, ws, (float*)d_out);
}

// Round 17
// 109.027 us; speedup vs baseline: 1.0488x; 1.0488x over previous
//
#include <hip/hip_runtime.h>
#include <math.h>

// CrowdDet RetinaNet loss constants
#define POS_T 0.5f
#define NEG_T 0.4f
#define F_ALPHA 0.25f
#define SL1_BETA 0.1f
#define SENT 3.0e8f

// Pruning geometry (validated R10-R16): 8x8 cells of 128px, 6 area classes.
#define NCELL 8
#define NCLASS 6
#define NB (NCELL * NCELL * NCLASS)   // 384 buckets
#define KEEP_T 0.37f
#define APT 4                          // anchors per thread in k1/k3 (nablk<=256)

// Anchor legacy-area class thresholds: 289 * 2.5^k (exact in f32).
__device__ __constant__ float AT[7] = {
    289.f, 722.5f, 1806.25f, 4515.625f, 11289.0625f, 28222.65625f, 70556.640625f};

__device__ __forceinline__ float smooth_l1(float d) {
    d = fabsf(d);
    return d < SL1_BETA ? 0.5f * d * d / SL1_BETA : d - SL1_BETA;
}

// Broadcast lane g's value to all lanes (v_readlane, uniform g).
__device__ __forceinline__ float rlf(float x, int g) {
    return __int_as_float(__builtin_amdgcn_readlane(__float_as_int(x), g));
}

__device__ __forceinline__ int bucket_of(const float4 av) {
    const float aw = av.z - av.x + 1.f, ah = av.w - av.y + 1.f;
    const float Aa = aw * ah;
    const float cx = 0.5f * (av.x + av.z);
    const float cy = 0.5f * (av.y + av.w);
    const int cxi = min(NCELL - 1, max(0, (int)(cx * (1.0f / 128.f))));
    const int cyi = min(NCELL - 1, max(0, (int)(cy * (1.0f / 128.f))));
    const int k = (Aa > AT[1]) + (Aa > AT[2]) + (Aa > AT[3])
                + (Aa > AT[4]) + (Aa > AT[5]);
    return (k << 6) | (cyi << 3) | cxi;
}

// ---- K1: anchor buckets + per-block LDS hist; prefill sortedA/wavebkt/ws ---
// Thread t handles ai = blk*1024 + u*256 + t (unit-stride coalesced).
__global__ __launch_bounds__(256) void k1_assign(
    const float* __restrict__ anchors,
    int* __restrict__ bucketid, int* __restrict__ blockhist, // [nablk][NB]
    int* __restrict__ sortedA, int* __restrict__ wavebkt,
    double* __restrict__ ws,
    int A, int PADTOT, int NWPAD, int nablk)
{
#pragma clang fp contract(off)
    __shared__ int lh[NB];
    const int t = threadIdx.x;
    for (int i = t; i < NB; i += 256) lh[i] = 0;
    __syncthreads();

    const int gid = blockIdx.x * 256 + t;
    if (gid < 50) ws[gid] = 0.0;                 // accumulators + done ctr
    const int stride = nablk * 256;
    for (int j = gid; j < PADTOT; j += stride) sortedA[j] = -1;
    for (int j = gid; j < NWPAD; j += stride) wavebkt[j] = -1;

    #pragma unroll
    for (int u = 0; u < APT; ++u) {
        const int ai = blockIdx.x * (256 * APT) + u * 256 + t;
        if (ai < A) {
            const float4 av = *reinterpret_cast<const float4*>(anchors + 4 * (size_t)ai);
            const int bk = bucket_of(av);
            bucketid[ai] = bk;
            atomicAdd(&lh[bk], 1);               // LDS atomic, cheap
        }
    }
    __syncthreads();
    for (int j = t; j < NB; j += 256)
        blockhist[(size_t)blockIdx.x * NB + j] = lh[j];
}

// ---- K2: per-bucket scan of block hists + SoA candidate lists (validated) --
__global__ __launch_bounds__(256) void k2_scan_lists(
    int* __restrict__ bh, int* __restrict__ totals,
    const float* __restrict__ gt, const float* __restrict__ im_info,
    int* __restrict__ cnt_arr, float* __restrict__ soa,
    float4* __restrict__ eLo, float* __restrict__ eCls,
    int nablk, int G, int NCH, int B)
{
#pragma clang fp contract(off)
    const int bk = blockIdx.x, t = threadIdx.x;

    // Phase 1: exclusive scan of bh[blk][bk] over blk (nablk <= 256).
    __shared__ int s[256];
    const int v = (t < nablk) ? bh[(size_t)t * NB + bk] : 0;
    s[t] = v;
    __syncthreads();
    for (int d = 1; d < 256; d <<= 1) {
        const int u = (t >= d) ? s[t - d] : 0;
        __syncthreads();
        s[t] += u;
        __syncthreads();
    }
    if (t < nablk) bh[(size_t)t * NB + bk] = s[t] - v;   // exclusive prefix
    if (t == 255) totals[bk] = s[255];

    // Phase 2: candidate lists, one batch per wave (validated keep-test;
    // compaction preserves ascending gt order -> first-max tie-break intact).
    const int wid = t >> 6, lane = t & 63;
    const int cxi = bk & 7, cyi = (bk >> 3) & 7, k = bk >> 6;
    const float cx0 = cxi * 128.f, cx1 = cx0 + 128.f;
    const float cy0 = cyi * 128.f, cy1 = cy0 + 128.f;
    const float Alo = AT[k], Ahi = AT[k + 1];

    for (int b = wid; b < B; b += 4) {
        const int nv = __builtin_amdgcn_readfirstlane((int)im_info[b * 6 + 5]);
        const int li = b * NB + bk;
        float* __restrict__ sb = soa + (size_t)li * NCH * 40;
        const size_t eb = (size_t)li * G;

        int cnt = 0;
        for (int base = 0; base < nv; base += 64) {
            const int j = base + lane;
            bool keep = false;
            float g0 = 0.f, g1 = 0.f, g2 = 0.f, g3 = 0.f, cls = 0.f;
            float area = 0.f, g2p = 0.f, g3p = 0.f;
            if (j < nv) {
                const float* sp = gt + ((size_t)b * G + j) * 5;
                g0 = sp[0]; g1 = sp[1]; g2 = sp[2]; g3 = sp[3]; cls = sp[4];
                area = (g2 - g0 + 1.f) * (g3 - g1 + 1.f);   // exact ref order
                g2p = g2 + 1.f; g3p = g3 + 1.f;             // pre-added +1
                const float wg = g2p - g0;
                const float hg = g3p - g1;
                const float ox = fminf(cx1 + 129.f, g2p) - fmaxf(cx0 - 128.f, g0);
                const float oy = fminf(cy1 + 129.f, g3p) - fmaxf(cy0 - 128.f, g1);
                keep = (ox >= KEEP_T * wg) && (oy >= KEEP_T * hg)
                    && (area >= KEEP_T * Alo) && (KEEP_T * area <= Ahi);
            }
            const unsigned long long m = __ballot(keep);
            if (keep) {
                const int pos = cnt + __popcll(m & ((1ull << lane) - 1ull));
                float* c = sb + (size_t)(pos >> 3) * 40 + (pos & 7);
                c[0] = g0; c[8] = g1; c[16] = g2p; c[24] = g3p; c[32] = area;
                eLo[eb + pos] = make_float4(g0, g1, g2, g3);
                eCls[eb + pos] = cls;
            }
            cnt += __popcll(m);
        }
        if (lane == 0) cnt_arr[li] = cnt;
    }
}

// ---- K3: bases + wave table + PRE-GATHER anchor data into sorted slots -----
// Linear (coalesced) reads of anchors/pred_cls; scattered fire-and-forget
// writes. Moves the sort's irreducible data movement to the latency-tolerant
// write side so k4 reads everything coalesced.
__global__ __launch_bounds__(256) void k3_place(
    const float* __restrict__ anchors, const float* __restrict__ pred_cls,
    const int* __restrict__ bucketid, const int* __restrict__ bh,
    const int* __restrict__ totals,
    int* __restrict__ sortedA, float4* __restrict__ sortedAnc,
    float4* __restrict__ sortedMeta, float2* __restrict__ sortedPc,
    int* __restrict__ wavebkt, int A, int B)
{
#pragma clang fp contract(off)
    __shared__ int lh[NB];
    __shared__ int sbase[NB];
    const int t = threadIdx.x, blk = blockIdx.x;
    for (int i = t; i < NB; i += 256) lh[i] = 0;
    if (t < 64) {
        int carry = 0;
        #pragma unroll
        for (int r = 0; r < NB / 64; ++r) {
            int v = ((totals[r * 64 + t] + 63) >> 6) << 6;   // padded count
            const int orig = v;
            for (int d = 1; d < 64; d <<= 1) {
                const int u = __shfl_up(v, d);
                if (t >= d) v += u;
            }
            sbase[r * 64 + t] = carry + v - orig;   // exclusive padded base
            carry += __shfl(v, 63);
        }
    }
    __syncthreads();

    if (blk == 0) {        // wave->bucket table
        for (int bk = t; bk < NB; bk += 256) {
            const int nw = (totals[bk] + 63) >> 6;
            const int wb = sbase[bk] >> 6;
            for (int w = 0; w < nw; ++w) wavebkt[wb + w] = bk;
        }
    }

    #pragma unroll
    for (int u = 0; u < APT; ++u) {
        const int ai = blk * (256 * APT) + u * 256 + t;   // unit-stride reads
        if (ai < A) {
            const int bk = bucketid[ai];
            const int lrk = atomicAdd(&lh[bk], 1);
            const int slot = sbase[bk] + bh[(size_t)blk * NB + bk] + lrk;
            const float4 av = *reinterpret_cast<const float4*>(anchors + 4 * (size_t)ai);
            const float aw = av.z - av.x + 1.f;             // exact ref ops
            const float ah = av.w - av.y + 1.f;
            sortedA[slot] = ai;
            sortedAnc[slot] = make_float4(av.x, av.y, av.z + 1.f, av.w + 1.f);
            sortedMeta[slot] = make_float4(aw * ah, aw, ah, 0.f);
            const float pc0 = pred_cls[ai];
            const float pc1 = (B > 1) ? pred_cls[(size_t)A + ai] : 0.f;
            sortedPc[slot] = make_float2(pc0, pc1);
        }
    }
}

// ---- K4: main loss. Wave = (anchor-wave, batch). ALL hot reads coalesced
//          (pre-gathered slot arrays); list scan via per-lane load +
//          v_readlane broadcast (R16-validated numerics, absmax 0.0). --------
__global__ __launch_bounds__(256) void k4_loss(
    const float* __restrict__ pred_reg,
    const int* __restrict__ sortedA, const float4* __restrict__ sortedAnc,
    const float4* __restrict__ sortedMeta, const float2* __restrict__ sortedPc,
    const int* __restrict__ wavebkt,
    const int* __restrict__ cnt_arr, const float* __restrict__ soa,
    const float4* __restrict__ eLo, const float* __restrict__ eCls,
    int A, int G, int NCH, int B, int NWMAX,
    double* __restrict__ ws, float* __restrict__ out)
{
#pragma clang fp contract(off)
    const int t = threadIdx.x;
    const int lane = t & 63;
    const int wv = __builtin_amdgcn_readfirstlane(blockIdx.x * 4 + (t >> 6));
    const int wgid = wv / B;
    const int b = wv - wgid * B;
    const int bk = (wgid < NWMAX)
        ? __builtin_amdgcn_readfirstlane(wavebkt[wgid]) : -1;

    float lc = 0.f, lr = 0.f;
    int fg = 0;

    if (bk >= 0) {
        const int slot = wgid * 64 + lane;
        const int ai = sortedA[slot];             // coalesced; -1 = pad slot
        const bool live = ai >= 0;
        const int a = max(ai, 0);

        const float4 anc = sortedAnc[slot];       // {a0, a1, a2p, a3p} coalesced
        const float4 meta = sortedMeta[slot];     // {area_a, aw, ah, -}
        const float2 pc = sortedPc[slot];
        const float a0 = anc.x, a1 = anc.y, a2p = anc.z, a3p = anc.w;
        const float area_a = meta.x, aw = meta.y, ah = meta.z;

        const int li = b * NB + bk;
        const int cnt = __builtin_amdgcn_readfirstlane(cnt_arr[li]);
        const float* lbase = soa + (size_t)li * NCH * 40;

        // Division-free IoU argmax (validated): strict > == first-max;
        // only g < cnt is ever broadcast. Pad slots compute garbage, masked
        // by `live` (NaN compares are false -> argp stays in [0,cnt)).
        float bi = -1.f, bS = 1.f;
        int argp = 0;
        for (int base = 0; base < cnt; base += 64) {
            const int j = base + lane;
            float q0 = 0.f, q1 = 0.f, q2 = 0.f, q3 = 0.f, q4 = 0.f;
            if (j < cnt) {
                const float* cp = lbase + (size_t)(j >> 3) * 40 + (j & 7);
                q0 = cp[0]; q1 = cp[8]; q2 = cp[16]; q3 = cp[24]; q4 = cp[32];
            }
            const int m = min(64, cnt - base);
            for (int g = 0; g < m; ++g) {          // uniform trip count
                const float g0  = rlf(q0, g);      // v_readlane broadcasts
                const float g1  = rlf(q1, g);
                const float g2p = rlf(q2, g);
                const float g3p = rlf(q3, g);
                const float sg  = rlf(q4, g);
                const float iw = fminf(a2p, g2p) - fmaxf(a0, g0);
                const float ih = fminf(a3p, g3p) - fmaxf(a1, g1);
                const float inter = fmaxf(iw, 0.f) * fmaxf(ih, 0.f);
                const float S = area_a + sg;
                const bool upd = inter * bS > bi * S;
                bi   = upd ? inter      : bi;
                bS   = upd ? S          : bS;
                argp = upd ? (base + g) : argp;
            }
        }

        if (live) {
            // ONE division, exact ref expr: inter/((area_a+area_g)-inter).
            // cnt==0 -> max_ov=-0.5 -> bg (validated: pruned ious < 0.37).
            const float max_ov = bi / (bS - bi);

            float label = 0.f;
            bool valid = true;
            if (max_ov >= POS_T) {
                label = eCls[(size_t)li * G + argp];   // wave-local 2 lines
            } else if (max_ov >= NEG_T) {
                valid = false;                 // ignore band
            }
            const int f = (label > 0.f) ? 1 : 0;
            fg = f;

            if (valid) {
                const float x = (b == 0) ? pc.x : pc.y;   // pre-gathered
                const float p = 1.f / (1.f + expf(-x));
                const float l1p = log1pf(expf(-fabsf(x)));
                const float log_p  = fminf(x, 0.f) - l1p;    // log_sigmoid(x)
                const float log_np = fminf(-x, 0.f) - l1p;   // log_sigmoid(-x)
                const float pos = (label == 1.f) ? 1.f : 0.f;
                const float omp = 1.f - p;
                lc = -(F_ALPHA * pos * (omp * omp) * log_p
                       + (1.f - F_ALPHA) * (1.f - pos) * (p * p) * log_np);
            }

            if (f) {
                const float4 gb = eLo[(size_t)li * G + argp];  // originals
                const float gw = gb.z - gb.x + 1.f;
                const float gh = gb.w - gb.y + 1.f;
                const float gx = gb.x + 0.5f * gw;
                const float gy = gb.y + 0.5f * gh;
                const float axc = a0 + 0.5f * aw;
                const float ayc = a1 + 0.5f * ah;
                const float t0 = (gx - axc) / aw;
                const float t1 = (gy - ayc) / ah;
                const float t2 = logf(gw / aw);
                const float t3 = logf(gh / ah);
                const float4 rr = *reinterpret_cast<const float4*>(
                    pred_reg + 4 * ((size_t)b * A + a));   // rare fg gather
                lr = smooth_l1(rr.x - t0) + smooth_l1(rr.y - t1)
                   + smooth_l1(rr.z - t2) + smooth_l1(rr.w - t3);
            }
        }
    }

    // wave64 reduction + block atomics + fused last-block finalize (validated).
    for (int off = 32; off > 0; off >>= 1) {
        lc += __shfl_down(lc, off);
        lr += __shfl_down(lr, off);
        fg += __shfl_down(fg, off);
    }
    __shared__ float s_lc[4], s_lr[4];
    __shared__ int s_np[4];
    const int wid = t >> 6;
    if (lane == 0) { s_lc[wid] = lc; s_lr[wid] = lr; s_np[wid] = fg; }
    __syncthreads();
    if (t == 0) {
        const float tlc = s_lc[0] + s_lc[1] + s_lc[2] + s_lc[3];
        const float tlr = s_lr[0] + s_lr[1] + s_lr[2] + s_lr[3];
        const int   tnp = s_np[0] + s_np[1] + s_np[2] + s_np[3];
        __hip_atomic_fetch_add(&ws[0],  (double)tlc, __ATOMIC_RELAXED, __HIP_MEMORY_SCOPE_AGENT);
        __hip_atomic_fetch_add(&ws[16], (double)tlr, __ATOMIC_RELAXED, __HIP_MEMORY_SCOPE_AGENT);
        __hip_atomic_fetch_add(&ws[32], (double)tnp, __ATOMIC_RELAXED, __HIP_MEMORY_SCOPE_AGENT);
        __threadfence();
        int* done = (int*)(ws + 48);
        const int prev = __hip_atomic_fetch_add(done, 1, __ATOMIC_ACQ_REL,
                                                __HIP_MEMORY_SCOPE_AGENT);
        if (prev == (int)gridDim.x - 1) {
            __threadfence();
            const double cls_s = __hip_atomic_load(&ws[0],  __ATOMIC_ACQUIRE, __HIP_MEMORY_SCOPE_AGENT);
            const double reg_s = __hip_atomic_load(&ws[16], __ATOMIC_ACQUIRE, __HIP_MEMORY_SCOPE_AGENT);
            const double np_s  = __hip_atomic_load(&ws[32], __ATOMIC_ACQUIRE, __HIP_MEMORY_SCOPE_AGENT);
            const double npos = np_s < 1.0 ? 1.0 : np_s;
            const double norm = 0.9 * 100.0 + 0.1 * npos;
            out[0] = (float)(cls_s / norm);
            out[1] = (float)(reg_s / norm);
        }
    }
}

extern "C" void kernel_launch(void* const* d_in, const int* in_sizes, int n_in,
                              void* d_out, int out_size, void* d_ws, size_t ws_size,
                              hipStream_t stream) {
    const float* pred_cls = (const float*)d_in[0];
    const float* pred_reg = (const float*)d_in[1];
    const float* anchors  = (const float*)d_in[2];
    const float* gt_boxes = (const float*)d_in[3];
    const float* im_info  = (const float*)d_in[4];

    const int A = in_sizes[2] / 4;
    const int B = in_sizes[4] / 6;
    const int G = in_sizes[3] / (B * 5);
    const int NCH = (G + 7) / 8;                 // chunks per list (ceil)
    const int nablk = (A + 256 * APT - 1) / (256 * APT);   // <= 256 required
    const int PADTOT = A + NB * 64;              // padded sorted-slot bound
    const int NWMAX = (A + 63) / 64 + NB;        // anchor-wave bound
    const int NWPAD = NWMAX + 8;
    const int K4B = (NWMAX * B + 3) / 4;         // 4 waves per block

    // ---- ws layout ----
    char* base = (char*)d_ws;
    double* ws = (double*)base;                  // [0,512): accum + done ctr
    size_t off = 512;
    float* soa = (float*)(base + off);       off += (size_t)B * NB * NCH * 40 * 4;
    off = (off + 255) & ~(size_t)255;
    float4* eLo = (float4*)(base + off);     off += (size_t)B * NB * G * 16;
    float* eCls = (float*)(base + off);      off += (size_t)B * NB * G * 4;
    off = (off + 255) & ~(size_t)255;
    int* cnt_arr = (int*)(base + off);       off += (size_t)B * NB * 4;
    int* bucketid = (int*)(base + off);      off += (size_t)A * 4;
    int* sortedA = (int*)(base + off);       off += (size_t)PADTOT * 4;
    off = (off + 255) & ~(size_t)255;
    float4* sortedAnc = (float4*)(base + off);  off += (size_t)PADTOT * 16;
    float4* sortedMeta = (float4*)(base + off); off += (size_t)PADTOT * 16;
    float2* sortedPc = (float2*)(base + off);   off += (size_t)PADTOT * 8;
    int* wavebkt = (int*)(base + off);       off += (size_t)NWPAD * 4;
    off = (off + 255) & ~(size_t)255;
    int* blockhist = (int*)(base + off);     off += (size_t)nablk * NB * 4;
    int* totals = (int*)(base + off);        off += (size_t)NB * 4;

    k1_assign<<<nablk, 256, 0, stream>>>(anchors, bucketid, blockhist,
                                         sortedA, wavebkt, ws,
                                         A, PADTOT, NWPAD, nablk);
    k2_scan_lists<<<NB, 256, 0, stream>>>(blockhist, totals, gt_boxes, im_info,
                                          cnt_arr, soa, eLo, eCls,
                                          nablk, G, NCH, B);
    k3_place<<<nablk, 256, 0, stream>>>(anchors, pred_cls, bucketid, blockhist,
                                        totals, sortedA, sortedAnc, sortedMeta,
                                        sortedPc, wavebkt, A, B);
    k4_loss<<<K4B, 256, 0, stream>>>(pred_reg, sortedA, sortedAnc, sortedMeta,
                                     sortedPc, wavebkt, cnt_arr, soa, eLo, eCls,
                                     A, G, NCH, B, NWMAX, ws, (float*)d_out);
}

// Round 18
// 56.597 us; speedup vs baseline: 2.0204x; 1.9264x over previous
//
#include <hip/hip_runtime.h>
#include <math.h>

// CrowdDet RetinaNet loss constants
#define POS_T 0.5f
#define NEG_T 0.4f
#define F_ALPHA 0.25f
#define SL1_BETA 0.1f

// Pruning geometry (validated R10-R17): 8x8 cells of 128px, 6 area classes.
#define NCELL 8
#define NCLASS 6
#define NB (NCELL * NCELL * NCLASS)   // 384 buckets
#define KEEP_T 0.37f
#define APT 4                          // anchors per thread in k1/k3

// Anchor legacy-area class thresholds: 289 * 2.5^k (exact in f32).
__device__ __constant__ float AT[7] = {
    289.f, 722.5f, 1806.25f, 4515.625f, 11289.0625f, 28222.65625f, 70556.640625f};

__device__ __forceinline__ float smooth_l1(float d) {
    d = fabsf(d);
    return d < SL1_BETA ? 0.5f * d * d / SL1_BETA : d - SL1_BETA;
}

__device__ __forceinline__ int bucket_of(const float4 av) {
    const float aw = av.z - av.x + 1.f, ah = av.w - av.y + 1.f;
    const float Aa = aw * ah;
    const float cx = 0.5f * (av.x + av.z);
    const float cy = 0.5f * (av.y + av.w);
    const int cxi = min(NCELL - 1, max(0, (int)(cx * (1.0f / 128.f))));
    const int cyi = min(NCELL - 1, max(0, (int)(cy * (1.0f / 128.f))));
    const int k = (Aa > AT[1]) + (Aa > AT[2]) + (Aa > AT[3])
                + (Aa > AT[4]) + (Aa > AT[5]);
    return (k << 6) | (cyi << 3) | cxi;
}

// ---- K1: ws zero + anchor buckets + per-block LDS histogram ---------------
__global__ __launch_bounds__(256) void k1_assign(
    const float* __restrict__ anchors,
    int* __restrict__ bucketid, int* __restrict__ blockhist, // [nblk][NB]
    double* __restrict__ ws, int A)
{
#pragma clang fp contract(off)
    __shared__ int lh[NB];
    const int t = threadIdx.x;
    for (int i = t; i < NB; i += 256) lh[i] = 0;
    __syncthreads();

    const int gid = blockIdx.x * 256 + t;
    if (gid < 34) ws[gid] = 0.0;                 // loss accumulators

    #pragma unroll
    for (int u = 0; u < APT; ++u) {
        const int ai = blockIdx.x * (256 * APT) + u * 256 + t;  // unit-stride
        if (ai < A) {
            const float4 av = *reinterpret_cast<const float4*>(anchors + 4 * (size_t)ai);
            const int bk = bucket_of(av);
            bucketid[ai] = bk;
            atomicAdd(&lh[bk], 1);               // LDS atomic, cheap
        }
    }
    __syncthreads();
    for (int j = t; j < NB; j += 256)
        blockhist[(size_t)blockIdx.x * NB + j] = lh[j];   // coalesced burst
}

// ---- K2: per-bucket scan of block hists + COMPACT candidate lists ---------
// Direct record layout (R14-validated, absmax 0.0): qLo {g0,g1,g2+1,g3+1},
// qA area, eLo {g0,g1,g2,g3} originals, eCls cls. Ascending gt order kept.
__global__ __launch_bounds__(256) void k2_scan_lists(
    int* __restrict__ bh, int* __restrict__ totals,
    const float* __restrict__ gt, const float* __restrict__ im_info,
    int* __restrict__ cnt_arr,
    float4* __restrict__ qLo, float* __restrict__ qA,
    float4* __restrict__ eLo, float* __restrict__ eCls,
    int nblk, int G, int Gp, int B)
{
#pragma clang fp contract(off)
    const int bk = blockIdx.x, t = threadIdx.x;

    // Phase 1: exclusive scan of bh[blk][bk] over blk (nblk <= 256).
    __shared__ int s[256];
    const int v = (t < nblk) ? bh[(size_t)t * NB + bk] : 0;
    s[t] = v;
    __syncthreads();
    for (int d = 1; d < 256; d <<= 1) {
        const int u = (t >= d) ? s[t - d] : 0;
        __syncthreads();
        s[t] += u;
        __syncthreads();
    }
    if (t < nblk) bh[(size_t)t * NB + bk] = s[t] - v;   // exclusive prefix
    if (t == 255) totals[bk] = s[255];

    // Phase 2: candidate lists, one batch per wave (validated keep-test).
    const int wid = t >> 6, lane = t & 63;
    const int cxi = bk & 7, cyi = (bk >> 3) & 7, k = bk >> 6;
    const float cx0 = cxi * 128.f, cx1 = cx0 + 128.f;
    const float cy0 = cyi * 128.f, cy1 = cy0 + 128.f;
    const float Alo = AT[k], Ahi = AT[k + 1];

    for (int b = wid; b < B; b += 4) {
        const int nv = __builtin_amdgcn_readfirstlane((int)im_info[b * 6 + 5]);
        const int li = b * NB + bk;
        const size_t lb = (size_t)li * Gp;

        int cnt = 0;
        for (int base = 0; base < nv; base += 64) {
            const int j = base + lane;
            bool keep = false;
            float g0 = 0.f, g1 = 0.f, g2 = 0.f, g3 = 0.f, cls = 0.f;
            float area = 0.f, g2p = 0.f, g3p = 0.f;
            if (j < nv) {
                const float* sp = gt + ((size_t)b * G + j) * 5;
                g0 = sp[0]; g1 = sp[1]; g2 = sp[2]; g3 = sp[3]; cls = sp[4];
                area = (g2 - g0 + 1.f) * (g3 - g1 + 1.f);   // exact ref order
                g2p = g2 + 1.f; g3p = g3 + 1.f;             // pre-added +1
                const float wg = g2p - g0;
                const float hg = g3p - g1;
                const float ox = fminf(cx1 + 129.f, g2p) - fmaxf(cx0 - 128.f, g0);
                const float oy = fminf(cy1 + 129.f, g3p) - fmaxf(cy0 - 128.f, g1);
                keep = (ox >= KEEP_T * wg) && (oy >= KEEP_T * hg)
                    && (area >= KEEP_T * Alo) && (KEEP_T * area <= Ahi);
            }
            const unsigned long long m = __ballot(keep);
            if (keep) {
                const int pos = cnt + __popcll(m & ((1ull << lane) - 1ull));
                qLo[lb + pos] = make_float4(g0, g1, g2p, g3p);
                qA[lb + pos] = area;
                eLo[lb + pos] = make_float4(g0, g1, g2, g3);
                eCls[lb + pos] = cls;
            }
            cnt += __popcll(m);
        }
        if (lane == 0) cnt_arr[li] = cnt;
    }
}

// ---- K3: bases + place anchors + PRE-GATHER per-anchor data to slot order --
// Linear (coalesced) reads of anchors/pred_cls; scattered latency-tolerant
// writes so k5 reads everything coalesced. Math verbatim R17 (absmax 0.0).
__global__ __launch_bounds__(256) void k3_place(
    const float* __restrict__ anchors, const float* __restrict__ pred_cls,
    const int* __restrict__ bucketid, const int* __restrict__ bh,
    const int* __restrict__ totals,
    int* __restrict__ sortedA, int* __restrict__ sortedbkt,
    float4* __restrict__ sortedAnc, float4* __restrict__ sortedMeta,
    float2* __restrict__ sortedPc, int A, int B)
{
#pragma clang fp contract(off)
    __shared__ int lh[NB];
    __shared__ int sbase[NB];
    const int t = threadIdx.x, blk = blockIdx.x;
    for (int i = t; i < NB; i += 256) lh[i] = 0;
    if (t < 64) {
        int carry = 0;
        #pragma unroll
        for (int r = 0; r < NB / 64; ++r) {
            int v = totals[r * 64 + t];            // exact (unpadded) bases
            const int orig = v;
            for (int d = 1; d < 64; d <<= 1) {
                const int u = __shfl_up(v, d);
                if (t >= d) v += u;
            }
            sbase[r * 64 + t] = carry + v - orig;  // exclusive
            carry += __shfl(v, 63);
        }
    }
    __syncthreads();

    #pragma unroll
    for (int u = 0; u < APT; ++u) {
        const int ai = blk * (256 * APT) + u * 256 + t;   // unit-stride reads
        if (ai < A) {
            const int bk = bucketid[ai];
            const int lrk = atomicAdd(&lh[bk], 1);
            const int slot = sbase[bk] + bh[(size_t)blk * NB + bk] + lrk;
            const float4 av = *reinterpret_cast<const float4*>(anchors + 4 * (size_t)ai);
            const float aw = av.z - av.x + 1.f;            // exact ref ops
            const float ah = av.w - av.y + 1.f;
            sortedA[slot] = ai;
            sortedbkt[slot] = bk;
            sortedAnc[slot] = make_float4(av.x, av.y, av.z + 1.f, av.w + 1.f);
            sortedMeta[slot] = make_float4(aw * ah, aw, ah, 0.f);
            const float pc0 = pred_cls[ai];
            const float pc1 = (B > 1) ? pred_cls[(size_t)A + ai] : 0.f;
            sortedPc[slot] = make_float2(pc0, pc1);
        }
    }
}

// ---- K5: main loss. Slot-order coalesced anchor reads; list walk has ZERO
//          indirection (induction-address broadcast loads -> pipelined);
//          both batches per thread. Numerics verbatim validated kernels. ----
__global__ __launch_bounds__(256) void retina_loss_kernel(
    const float* __restrict__ pred_reg,
    const int* __restrict__ sortedA, const int* __restrict__ sortedbkt,
    const float4* __restrict__ sortedAnc, const float4* __restrict__ sortedMeta,
    const float2* __restrict__ sortedPc, const float* __restrict__ pred_cls,
    const int* __restrict__ cnt_arr,
    const float4* __restrict__ qLo, const float* __restrict__ qA,
    const float4* __restrict__ eLo, const float* __restrict__ eCls,
    int A, int Gp, int B,
    double* __restrict__ ws)
{
#pragma clang fp contract(off)
    const int t = threadIdx.x;
    const int i_raw = blockIdx.x * 256 + t;
    const bool live = i_raw < A;
    const int i = min(i_raw, A - 1);

    const int a = sortedA[i];                 // coalesced
    const int bk = sortedbkt[i];              // near-uniform per wave
    const float4 anc = sortedAnc[i];          // {a0, a1, a2p, a3p}
    const float4 meta = sortedMeta[i];        // {area_a, aw, ah, -}
    const float2 pc = sortedPc[i];
    const float a0 = anc.x, a1 = anc.y, a2p = anc.z, a3p = anc.w;
    const float area_a = meta.x, aw = meta.y, ah = meta.z;

    float lc = 0.f, lr = 0.f;
    int fg = 0;

    for (int b = 0; b < B; ++b) {
        const int li = b * NB + bk;
        const int cnt = cnt_arr[li];
        const size_t lb = (size_t)li * Gp;

        // Division-free IoU argmax (validated): iou monotone in inter/S =>
        // strict cross-mul > == first-max (jnp.argmax tie-break). No ids[]
        // indirection: address is induction-only -> loads pipeline ahead.
        float bi = -1.f, bS = 1.f;
        int argp = 0;
        for (int g = 0; g < cnt; ++g) {
            const float4 q = qLo[lb + g];     // broadcast (uniform-ish bk)
            const float sg = qA[lb + g];
            const float iw = fminf(a2p, q.z) - fmaxf(a0, q.x);
            const float ih = fminf(a3p, q.w) - fmaxf(a1, q.y);
            const float inter = fmaxf(iw, 0.f) * fmaxf(ih, 0.f);
            const float S = area_a + sg;
            const bool upd = inter * bS > bi * S;
            bi   = upd ? inter : bi;
            bS   = upd ? S     : bS;
            argp = upd ? g     : argp;
        }

        if (live) {
            // ONE division, exact ref expr: inter/((area_a+area_g)-inter).
            // cnt==0 -> max_ov=-0.5 -> bg (validated: pruned ious < 0.37).
            const float max_ov = bi / (bS - bi);

            float label = 0.f;
            bool valid = true;
            if (max_ov >= POS_T) {
                label = eCls[lb + argp];
            } else if (max_ov >= NEG_T) {
                valid = false;                 // ignore band
            }
            const int f = (label > 0.f) ? 1 : 0;
            fg += f;

            if (valid) {
                const float x = (b == 0) ? pc.x
                              : (b == 1) ? pc.y
                              : pred_cls[(size_t)b * A + a];
                const float p = 1.f / (1.f + expf(-x));
                const float l1p = log1pf(expf(-fabsf(x)));
                const float log_p  = fminf(x, 0.f) - l1p;    // log_sigmoid(x)
                const float log_np = fminf(-x, 0.f) - l1p;   // log_sigmoid(-x)
                const float pos = (label == 1.f) ? 1.f : 0.f;
                const float omp = 1.f - p;
                lc += -(F_ALPHA * pos * (omp * omp) * log_p
                        + (1.f - F_ALPHA) * (1.f - pos) * (p * p) * log_np);
            }

            if (f) {
                const float4 gb = eLo[lb + argp];      // originals
                const float gw = gb.z - gb.x + 1.f;
                const float gh = gb.w - gb.y + 1.f;
                const float gx = gb.x + 0.5f * gw;
                const float gy = gb.y + 0.5f * gh;
                const float axc = a0 + 0.5f * aw;
                const float ayc = a1 + 0.5f * ah;
                const float t0 = (gx - axc) / aw;
                const float t1 = (gy - ayc) / ah;
                const float t2 = logf(gw / aw);
                const float t3 = logf(gh / ah);
                const float4 rr = *reinterpret_cast<const float4*>(
                    pred_reg + 4 * ((size_t)b * A + a));   // rare fg gather
                lr += smooth_l1(rr.x - t0) + smooth_l1(rr.y - t1)
                    + smooth_l1(rr.z - t2) + smooth_l1(rr.w - t3);
            }
        }
    }

    // wave64 reduction + one relaxed-atomic triple per block (R12-proven;
    // NO per-block threadfence).
    for (int off = 32; off > 0; off >>= 1) {
        lc += __shfl_down(lc, off);
        lr += __shfl_down(lr, off);
        fg += __shfl_down(fg, off);
    }
    __shared__ float s_lc[4], s_lr[4];
    __shared__ int s_np[4];
    const int wid = t >> 6;
    const int lane = t & 63;
    if (lane == 0) { s_lc[wid] = lc; s_lr[wid] = lr; s_np[wid] = fg; }
    __syncthreads();
    if (t == 0) {
        const float tlc = s_lc[0] + s_lc[1] + s_lc[2] + s_lc[3];
        const float tlr = s_lr[0] + s_lr[1] + s_lr[2] + s_lr[3];
        const int   tnp = s_np[0] + s_np[1] + s_np[2] + s_np[3];
        __hip_atomic_fetch_add(&ws[0],  (double)tlc, __ATOMIC_RELAXED, __HIP_MEMORY_SCOPE_AGENT);
        __hip_atomic_fetch_add(&ws[16], (double)tlr, __ATOMIC_RELAXED, __HIP_MEMORY_SCOPE_AGENT);
        __hip_atomic_fetch_add(&ws[32], (double)tnp, __ATOMIC_RELAXED, __HIP_MEMORY_SCOPE_AGENT);
    }
}

__global__ void finalize_kernel(const double* __restrict__ ws, float* __restrict__ out) {
    if (threadIdx.x == 0 && blockIdx.x == 0) {
        const double npos = ws[32] < 1.0 ? 1.0 : ws[32];
        const double norm = 0.9 * 100.0 + 0.1 * npos;
        out[0] = (float)(ws[0] / norm);
        out[1] = (float)(ws[16] / norm);
    }
}

extern "C" void kernel_launch(void* const* d_in, const int* in_sizes, int n_in,
                              void* d_out, int out_size, void* d_ws, size_t ws_size,
                              hipStream_t stream) {
    const float* pred_cls = (const float*)d_in[0];
    const float* pred_reg = (const float*)d_in[1];
    const float* anchors  = (const float*)d_in[2];
    const float* gt_boxes = (const float*)d_in[3];
    const float* im_info  = (const float*)d_in[4];

    const int A = in_sizes[2] / 4;
    const int B = in_sizes[4] / 6;
    const int G = in_sizes[3] / (B * 5);
    const int Gp = (G + 7) & ~7;
    const int nblk = (A + 256 * APT - 1) / (256 * APT);   // <= 256 required

    // ---- ws layout ----
    char* base = (char*)d_ws;
    double* ws = (double*)base;                  // [0,512): accumulators
    size_t off = 512;
    float4* qLo = (float4*)(base + off);     off += (size_t)B * NB * Gp * 16;
    float* qA = (float*)(base + off);        off += (size_t)B * NB * Gp * 4;
    off = (off + 255) & ~(size_t)255;
    float4* eLo = (float4*)(base + off);     off += (size_t)B * NB * Gp * 16;
    float* eCls = (float*)(base + off);      off += (size_t)B * NB * Gp * 4;
    off = (off + 255) & ~(size_t)255;
    int* cnt_arr = (int*)(base + off);       off += (size_t)B * NB * 4;
    int* bucketid = (int*)(base + off);      off += (size_t)A * 4;
    int* sortedA = (int*)(base + off);       off += (size_t)A * 4;
    int* sortedbkt = (int*)(base + off);     off += (size_t)A * 4;
    off = (off + 255) & ~(size_t)255;
    float4* sortedAnc = (float4*)(base + off);  off += (size_t)A * 16;
    float4* sortedMeta = (float4*)(base + off); off += (size_t)A * 16;
    float2* sortedPc = (float2*)(base + off);   off += (size_t)A * 8;
    off = (off + 255) & ~(size_t)255;
    int* blockhist = (int*)(base + off);     off += (size_t)nblk * NB * 4;
    int* totals = (int*)(base + off);        off += (size_t)NB * 4;

    k1_assign<<<nblk, 256, 0, stream>>>(anchors, bucketid, blockhist, ws, A);
    k2_scan_lists<<<NB, 256, 0, stream>>>(blockhist, totals, gt_boxes, im_info,
                                          cnt_arr, qLo, qA, eLo, eCls,
                                          nblk, G, Gp, B);
    k3_place<<<nblk, 256, 0, stream>>>(anchors, pred_cls, bucketid, blockhist,
                                       totals, sortedA, sortedbkt, sortedAnc,
                                       sortedMeta, sortedPc, A, B);
    const int CH = (A + 255) / 256;
    retina_loss_kernel<<<CH, 256, 0, stream>>>(
        pred_reg, sortedA, sortedbkt, sortedAnc, sortedMeta, sortedPc,
        pred_cls, cnt_arr, qLo, qA, eLo, eCls, A, Gp, B, ws);
    finalize_kernel<<<1, 1, 0, stream>>>(ws, (float*)d_out);
}